// Round 20
// baseline (62.235 us; speedup 1.0000x reference)
//
#include <hip/hip_runtime.h>
#include <hip/hip_bf16.h>
#include <cstdint>

// Problem: B=8, N=1024, C=256, H=8, D=64.
// out[b,i,o] = sum_{h,d} V[b,i,h,d] * w[b,i,h] * Wout[o,h,d]
// w[b,i,h]   = sum_j exp(S_ij)/d_j ;  S = Q K^T / 8 ; d_j = sum_i exp(S_ij)
// Wq pre-scaled by 0.125*log2(e) in k_prep => exp(S/8) == exp2(Q'K^T).
//
// FRAGMENT-ORDERED layouts: every MFMA operand load is 64 lanes x 16B
// contiguous. Tile = [kk(2)][lane(64)][e(8)] shorts: lane l, elem e ->
// (row = strip*16 + (l&15), k = kk*32 + (l>>4)*8 + e).
//  Qf/Kf/Vf: [bh][strip(64)]  Fb: [b][strip(64)][s(4)]
//  Wtf: [m][h][fm(4)][s(4)]   Wobf: [nt][fc(4)][s(8)]
// Wgp = [slice(32)][bh][i] f32 partial row-weights.
//
// Round-20 change: k_qkv grid 1536 -> 3072 half-size blocks (64 i-rows,
// 1 strip/wave). At 4 blocks/CU this is exactly 3 full residency rounds
// (no 512-block half-empty tail round). Everything else = round-19.

typedef __attribute__((ext_vector_type(8))) short bf16x8;
typedef __attribute__((ext_vector_type(4))) float f32x4;

#define EXP2(x) __builtin_amdgcn_exp2f(x)
#define MFMA(a, b, c) __builtin_amdgcn_mfma_f32_16x16x32_bf16((a), (b), (c), 0, 0, 0)
#define QSCALE 0.18033688011112042f

static __device__ __forceinline__ uint32_t pk2(float x, float y) {
  union { __hip_bfloat162 h; uint32_t u; } c;
  c.h = __float22bfloat162_rn(float2{x, y});
  return c.u;
}
static __device__ __forceinline__ short cvt1(float f) {
  union { __hip_bfloat16 h; short s; } c;
  c.h = __float2bfloat16(f);
  return c.s;
}

// ---------------------------------------------------------------------------
// K0: unified prep. 1280 blocks x 256 = 327680 threads.
//  [0, 262144):       F fp32 -> Fb bf16 fragment order (reads coalesced)
//  [262144, 311296):  Wq/Wk/Wv -> Wtf (transposed, Q-scaled, fragment order)
//  [311296, 327680):  Wo -> Wobf (fragment order)
// ---------------------------------------------------------------------------
__global__ __launch_bounds__(256) void k_prep(
    const float* __restrict__ F,  const float* __restrict__ Wq,
    const float* __restrict__ Wk, const float* __restrict__ Wv,
    const float* __restrict__ Wo,
    short* __restrict__ Fb, short* __restrict__ Wtf, short* __restrict__ Wobf)
{
  const int gt = blockIdx.x * 256 + threadIdx.x;
  if (gt < 262144) {                    // F: b(8) x i(1024) x c8(32)
    const int b  = gt >> 15;
    const int r  = gt & 32767;
    const int c8 = r & 31;              // lane-fastest -> coalesced reads
    const int i  = r >> 5;
    const float* src = F + ((size_t)(b * 1024 + i)) * 256 + c8 * 8;
    const float4 v0 = *(const float4*)src;
    const float4 v1 = *(const float4*)(src + 4);
    uint32_t u[4] = {pk2(v0.x, v0.y), pk2(v0.z, v0.w),
                     pk2(v1.x, v1.y), pk2(v1.z, v1.w)};
    const int strip = i >> 4, lo = i & 15;
    const int s = c8 >> 3, kk = (c8 >> 2) & 1, hi = c8 & 3;
    *(uint4*)&Fb[(size_t)b * 262144 + (size_t)strip * 4096 + s * 1024 +
                 kk * 512 + (hi * 16 + lo) * 8] = *(uint4*)u;
  } else if (gt < 311296) {             // Wq/Wk/Wv: m(3) x c8(32) x n(512)
    const int wt = gt - 262144;
    const int m  = wt >> 14;
    const int r  = wt & 16383;
    const int n  = r & 511;             // lane-fastest -> coalesced reads
    const int c8 = r >> 9;
    const float* W = (m == 0) ? Wq : (m == 1) ? Wk : Wv;
    const float scale = (m == 0) ? QSCALE : 1.0f;
    short tmp[8];
#pragma unroll
    for (int j = 0; j < 8; ++j)
      tmp[j] = cvt1(W[(size_t)(c8 * 8 + j) * 512 + n] * scale);
    const int h = n >> 6, fm = (n >> 4) & 3, lo = n & 15;
    const int s = c8 >> 3, kk = (c8 >> 2) & 1, hi = c8 & 3;
    *(int4*)&Wtf[(size_t)(((m * 8 + h) * 4 + fm) * 4 + s) * 1024 +
                 kk * 512 + (hi * 16 + lo) * 8] = *(int4*)tmp;
  } else if (gt < 327680) {             // Wo: o(256) x k8(64)
    const int wo = gt - 311296;
    const int o  = wo >> 6;
    const int k8 = wo & 63;             // lane-fastest -> coalesced reads
    const float* src = Wo + (size_t)o * 512 + k8 * 8;
    const float4 v0 = *(const float4*)src;
    const float4 v1 = *(const float4*)(src + 4);
    uint32_t u[4] = {pk2(v0.x, v0.y), pk2(v0.z, v0.w),
                     pk2(v1.x, v1.y), pk2(v1.z, v1.w)};
    const int nt = o >> 6, fc = (o >> 4) & 3, lo = o & 15;
    const int s = k8 >> 3, kk = (k8 >> 2) & 1, hi = k8 & 3;
    *(uint4*)&Wobf[(size_t)((nt * 4 + fc) * 8 + s) * 1024 +
                   kk * 512 + (hi * 16 + lo) * 8] = *(uint4*)u;
  }
}

// ---------------------------------------------------------------------------
// K1: QKV projection, one mat per block. 3072 blocks x 256 (64 i-rows
// each, 1 strip/wave), no barriers. 4 blocks/CU -> exactly 3 full rounds.
// All loads fragment-ordered (coalesced).
// ---------------------------------------------------------------------------
__global__ __launch_bounds__(256, 4) void k_qkv(
    const short* __restrict__ Fb, const short* __restrict__ Wtf,
    short* __restrict__ Qf, short* __restrict__ Kf, short* __restrict__ Vf)
{
  const int hw = blockIdx.x, t = threadIdx.x;
  const int xcd  = hw & 7;
  const int slot = hw >> 3;              // 0..383
  const int mh   = slot >> 4;            // 0..23 = m*8+h
  const int sub  = slot & 15;
  const int g    = xcd * 16 + sub;       // 0..127 = (b, mt16), co-XCD
  const int m    = mh >> 3;
  const int h    = mh & 7;
  const int b    = g >> 4;
  const int mt   = g & 15;               // 64-row tile
  const int wv = t >> 6, l = t & 63, lo = l & 15, hi = l >> 4;

  f32x4 acc[4];  // [fm: d-block]; single i-strip per wave
#pragma unroll
  for (int i = 0; i < 4; ++i) acc[i] = (f32x4){0.f, 0.f, 0.f, 0.f};

  const short* fbase = Fb + (size_t)b * 262144;
  const short* wbase = Wtf + (size_t)(m * 8 + h) * 16384;
  const int strip = mt * 4 + wv;         // this wave's i-strip (0..63)

#pragma unroll
  for (int s = 0; s < 4; ++s) {
    bf16x8 bb[2];
#pragma unroll
    for (int kk = 0; kk < 2; ++kk)
      bb[kk] = *(const bf16x8*)(fbase + (size_t)strip * 4096 +
                                s * 1024 + kk * 512 + l * 8);
#pragma unroll
    for (int fm = 0; fm < 4; ++fm) {
      const short* wr = wbase + (size_t)(fm * 4 + s) * 1024 + l * 8;
      bf16x8 a0 = *(const bf16x8*)(wr);
      bf16x8 a1 = *(const bf16x8*)(wr + 512);
      acc[fm] = MFMA(a0, bb[0], acc[fm]);
      acc[fm] = MFMA(a1, bb[1], acc[fm]);
    }
  }

  // Epilogue: lane holds (i = strip*16+lo, d = fm*16+hi*4 + 0..3).
  // Fragment-order store: kk=fm>>1, hi'=(fm&1)*2+(hi>>1), e0=(hi&1)*4.
  short* O = (m == 0) ? Qf : (m == 1) ? Kf : Vf;
  const size_t obase = (size_t)(b * 8 + h) * 65536;
#pragma unroll
  for (int fm = 0; fm < 4; ++fm) {
    uint32_t u[2] = {pk2(acc[fm][0], acc[fm][1]),
                     pk2(acc[fm][2], acc[fm][3])};
    const int kk = fm >> 1;
    const int hip = (fm & 1) * 2 + (hi >> 1);
    const int e0 = (hi & 1) * 4;
    *(uint2*)&O[obase + (size_t)strip * 1024 + kk * 512 +
                (hip * 16 + lo) * 8 + e0] = *(uint2*)u;
  }
}

// ---------------------------------------------------------------------------
// K2: fused colsum+rowsum with E-cache. 64*NSLICE blocks; JW=1024/NSLICE.
// Pass 1: MFMA + exp2 once; E=exp2(S') stored bf16 in LDS ([JW][1024+8
// pad] -> 2-way bank alias, free) while d_j accumulates. Pass 2: pure LDS
// reduction w_i(partial) = sum_j E[j][i]/d_j -- no MFMA/exp2/Q-stream.
// ---------------------------------------------------------------------------
template <int NSLICE>
__global__ __launch_bounds__(256, 2) void k_attw(
    const short* __restrict__ Qf, const short* __restrict__ Kf,
    float* __restrict__ Wgp)
{
  constexpr int JW = 1024 / NSLICE;   // 32
  constexpr int NS = JW / 16;         // 2
  __shared__ short E[JW][1032];       // bf16 exp2(S'), +8 short pad
  __shared__ float Red[4 * JW];
  const int hw = blockIdx.x, t = threadIdx.x;
  const int xcd  = hw & 7;
  const int slot = hw >> 3;                  // 0..8*NSLICE-1
  const int bh   = xcd * 8 + slot / NSLICE;  // same-bh blocks co-XCD
  const int jb   = slot % NSLICE;
  const size_t base = (size_t)bh * 65536;
  const int wv = t >> 6, l = t & 63, lo = l & 15, hi = l >> 4;
  const short* qb = Qf + base;
  const short* kb = Kf + base;

  bf16x8 bk[NS][2];
#pragma unroll
  for (int js = 0; js < NS; ++js) {
    const short* kr = kb + (size_t)(jb * NS + js) * 1024 + l * 8;
    bk[js][0] = *(const bf16x8*)(kr);
    bk[js][1] = *(const bf16x8*)(kr + 512);
  }

  // -------- pass 1: d_j partials + E store. Wave wv: strips wv+8k+4p.
  float cs[NS];
#pragma unroll
  for (int js = 0; js < NS; ++js) cs[js] = 0.f;

  {
    bf16x8 a0[2], a1[2];
#pragma unroll
    for (int p = 0; p < 2; ++p) {
      const short* q = qb + (size_t)(wv + 4 * p) * 1024 + l * 8;
      a0[p] = *(const bf16x8*)(q);
      a1[p] = *(const bf16x8*)(q + 512);
    }
#pragma unroll 1
    for (int k = 0; k < 8; ++k) {
      bf16x8 n0[2], n1[2];
      if (k < 7) {
#pragma unroll
        for (int p = 0; p < 2; ++p) {
          const short* q = qb + (size_t)(wv + 8 * (k + 1) + 4 * p) * 1024 + l * 8;
          n0[p] = *(const bf16x8*)(q);
          n1[p] = *(const bf16x8*)(q + 512);
        }
      }
#pragma unroll
      for (int js = 0; js < NS; ++js) {
#pragma unroll
        for (int p = 0; p < 2; ++p) {
          f32x4 acc = (f32x4){0.f, 0.f, 0.f, 0.f};
          acc = MFMA(a0[p], bk[js][0], acc);
          acc = MFMA(a1[p], bk[js][1], acc);
          // lane holds S'[i = strip*16 + hi*4 + r][j = js*16 + lo]
          float e0 = EXP2(acc[0]), e1 = EXP2(acc[1]);
          float e2 = EXP2(acc[2]), e3 = EXP2(acc[3]);
          cs[js] += (e0 + e1) + (e2 + e3);
          uint32_t u[2] = {pk2(e0, e1), pk2(e2, e3)};
          const int strip = wv + 8 * k + 4 * p;
          *(uint2*)&E[js * 16 + lo][strip * 16 + hi * 4] = *(uint2*)u;
        }
      }
      if (k < 7) {
#pragma unroll
        for (int p = 0; p < 2; ++p) { a0[p] = n0[p]; a1[p] = n1[p]; }
      }
    }
  }

#pragma unroll
  for (int js = 0; js < NS; ++js) {
    cs[js] += __shfl_xor(cs[js], 16, 64);
    cs[js] += __shfl_xor(cs[js], 32, 64);
  }
  if (hi == 0) {
#pragma unroll
    for (int js = 0; js < NS; ++js) Red[wv * JW + js * 16 + lo] = cs[js];
  }
  __syncthreads();
  if (t < JW) {
    float d = Red[t] + Red[JW + t] + Red[2 * JW + t] + Red[3 * JW + t];
    Red[t] = __builtin_amdgcn_rcpf(d);
  }
  __syncthreads();

  // -------- pass 2: pure LDS reduction. Thread t owns i = 4t..4t+3.
  {
    const int i0 = t * 4;
    float w4[4] = {0.f, 0.f, 0.f, 0.f};
#pragma unroll
    for (int j = 0; j < JW; ++j) {
      const float rjj = Red[j];                       // broadcast read
      uint2 u = *(const uint2*)&E[j][i0];
      w4[0] = fmaf(__uint_as_float(u.x << 16),          rjj, w4[0]);
      w4[1] = fmaf(__uint_as_float(u.x & 0xffff0000u),  rjj, w4[1]);
      w4[2] = fmaf(__uint_as_float(u.y << 16),          rjj, w4[2]);
      w4[3] = fmaf(__uint_as_float(u.y & 0xffff0000u),  rjj, w4[3]);
    }
    float4 o = {w4[0], w4[1], w4[2], w4[3]};
    *(float4*)&Wgp[(size_t)jb * 65536 + (size_t)bh * 1024 + i0] = o;
  }
}

// ---------------------------------------------------------------------------
// K3: out = (V .* w) @ Wob^T; w = sum of NSLICE partials (LDS prologue).
// 512 blocks x 256; all fragment loads coalesced.
// ---------------------------------------------------------------------------
template <int NSLICE>
__global__ __launch_bounds__(256, 2) void k_out(
    const short* __restrict__ Vf, const float* __restrict__ Wgp,
    const short* __restrict__ Wobf, float* __restrict__ Out)
{
  __shared__ float Wl[8][64];
  const int hw = blockIdx.x, t = threadIdx.x;
  const int slot = hw >> 3;
  const int g    = (hw & 7) * 16 + (slot >> 2);
  const int nt   = slot & 3;
  const int b    = g >> 4;
  const int mt   = g & 15;
  const int n0   = nt * 64;
  const int m0   = mt * 64;
  const int wv = t >> 6, l = t & 63, lo = l & 15, hi = l >> 4;

#pragma unroll
  for (int e = t; e < 512; e += 256) {
    int s = e >> 6, i2 = e & 63;
    float sum = 0.f;
#pragma unroll
    for (int p = 0; p < NSLICE; ++p)
      sum += Wgp[(size_t)p * 65536 + (size_t)(b * 8 + s) * 1024 + m0 + i2];
    Wl[s][i2] = sum;
  }
  __syncthreads();

  f32x4 acc[4];
#pragma unroll
  for (int j = 0; j < 4; ++j) acc[j] = (f32x4){0.f, 0.f, 0.f, 0.f};

  const int strip = mt * 4 + wv;   // i-strip (0..63)

#pragma unroll 1
  for (int s = 0; s < 8; ++s) {
    const float w = Wl[s][wv * 16 + lo];
    const short* vt = Vf + (size_t)(b * 8 + s) * 65536 + (size_t)strip * 1024;
#pragma unroll
    for (int kk = 0; kk < 2; ++kk) {
      int4 raw = *(const int4*)(vt + kk * 512 + l * 8);
      uint32_t* u = (uint32_t*)&raw;
      uint32_t o[4];
#pragma unroll
      for (int j = 0; j < 4; ++j) {
        float f0 = __uint_as_float(u[j] << 16) * w;
        float f1 = __uint_as_float(u[j] & 0xffff0000u) * w;
        o[j] = pk2(f0, f1);
      }
      bf16x8 a = *(bf16x8*)o;
#pragma unroll
      for (int fc = 0; fc < 4; ++fc) {
        bf16x8 bfr = *(const bf16x8*)(Wobf + (size_t)((nt * 4 + fc) * 8 + s) * 1024 +
                                      kk * 512 + l * 8);
        acc[fc] = MFMA(a, bfr, acc[fc]);
      }
    }
  }

#pragma unroll
  for (int fc = 0; fc < 4; ++fc)
#pragma unroll
    for (int r = 0; r < 4; ++r) {
      int i = m0 + wv * 16 + hi * 4 + r;
      int o = n0 + fc * 16 + lo;
      Out[(size_t)(b * 1024 + i) * 256 + o] = acc[fc][r];
    }
}

// ---------------------------------------------------------------------------
extern "C" void kernel_launch(void* const* d_in, const int* in_sizes, int n_in,
                              void* d_out, int out_size, void* d_ws, size_t ws_size,
                              hipStream_t stream) {
  const float* F  = (const float*)d_in[0];
  const float* Wq = (const float*)d_in[1];
  const float* Wk = (const float*)d_in[2];
  const float* Wv = (const float*)d_in[3];
  const float* Wo = (const float*)d_in[4];
  float* out = (float*)d_out;

  char* ws = (char*)d_ws;
  short* Qf   = (short*)(ws);                                      // 8 MB
  short* Kf   = (short*)(ws + (size_t)(8  << 20));                 // 8 MB
  short* Vf   = (short*)(ws + (size_t)(16 << 20));                 // 8 MB
  short* Fb   = (short*)(ws + (size_t)(24 << 20));                 // 4 MB
  float* Wgp  = (float*)(ws + (size_t)(28 << 20));                 // 8 MB (32 slices)
  short* Wtf  = (short*)(ws + (size_t)(36 << 20));                 // 768 KB
  short* Wobf = (short*)(ws + (size_t)(36 << 20) + (768 << 10));   // 256 KB

  k_prep<<<dim3(1280), 256, 0, stream>>>(F, Wq, Wk, Wv, Wo, Fb, Wtf, Wobf);
  k_qkv <<<dim3(3072), 256, 0, stream>>>(Fb, Wtf, Qf, Kf, Vf);
  k_attw<32><<<dim3(2048), 256, 0, stream>>>(Qf, Kf, Wgp);
  k_out<32> <<<dim3(512),  256, 0, stream>>>(Vf, Wgp, Wobf, out);
}

// Round 21
// 56.928 us; speedup vs baseline: 1.0932x; 1.0932x over previous
//
#include <hip/hip_runtime.h>
#include <hip/hip_bf16.h>
#include <cstdint>

// Problem: B=8, N=1024, C=256, H=8, D=64.
// out[b,i,o] = sum_{h,d} V[b,i,h,d] * w[b,i,h] * Wout[o,h,d]
// w[b,i,h]   = sum_j exp(S_ij)/d_j ;  S = Q K^T / 8 ; d_j = sum_i exp(S_ij)
// Wq pre-scaled by 0.125*log2(e) in k_prep => exp(S/8) == exp2(Q'K^T).
//
// FINAL = round-17/19 configuration (best measured 57.2 us, reproduced).
// FRAGMENT-ORDERED layouts: every MFMA operand load is 64 lanes x 16B
// contiguous. Tile = [kk(2)][lane(64)][e(8)] shorts: lane l, elem e ->
// (row = strip*16 + (l&15), k = kk*32 + (l>>4)*8 + e).
//  Qf/Kf/Vf: [bh][strip(64)]  Fb: [b][strip(64)][s(4)]
//  Wtf: [m][h][fm(4)][s(4)]   Wobf: [nt][fc(4)][s(8)]
// Wgp = [slice(32)][bh][i] f32 partial row-weights.
// Grid shapes are at a measured local optimum: NSLICE=64 (+66%), 3072
// half-blocks qkv (+9%), and (256,6) bounds all regressed.

typedef __attribute__((ext_vector_type(8))) short bf16x8;
typedef __attribute__((ext_vector_type(4))) float f32x4;

#define EXP2(x) __builtin_amdgcn_exp2f(x)
#define MFMA(a, b, c) __builtin_amdgcn_mfma_f32_16x16x32_bf16((a), (b), (c), 0, 0, 0)
#define QSCALE 0.18033688011112042f

static __device__ __forceinline__ uint32_t pk2(float x, float y) {
  union { __hip_bfloat162 h; uint32_t u; } c;
  c.h = __float22bfloat162_rn(float2{x, y});
  return c.u;
}
static __device__ __forceinline__ short cvt1(float f) {
  union { __hip_bfloat16 h; short s; } c;
  c.h = __float2bfloat16(f);
  return c.s;
}

// ---------------------------------------------------------------------------
// K0: unified prep. 1280 blocks x 256 = 327680 threads.
//  [0, 262144):       F fp32 -> Fb bf16 fragment order (reads coalesced)
//  [262144, 311296):  Wq/Wk/Wv -> Wtf (transposed, Q-scaled, fragment order)
//  [311296, 327680):  Wo -> Wobf (fragment order)
// ---------------------------------------------------------------------------
__global__ __launch_bounds__(256) void k_prep(
    const float* __restrict__ F,  const float* __restrict__ Wq,
    const float* __restrict__ Wk, const float* __restrict__ Wv,
    const float* __restrict__ Wo,
    short* __restrict__ Fb, short* __restrict__ Wtf, short* __restrict__ Wobf)
{
  const int gt = blockIdx.x * 256 + threadIdx.x;
  if (gt < 262144) {                    // F: b(8) x i(1024) x c8(32)
    const int b  = gt >> 15;
    const int r  = gt & 32767;
    const int c8 = r & 31;              // lane-fastest -> coalesced reads
    const int i  = r >> 5;
    const float* src = F + ((size_t)(b * 1024 + i)) * 256 + c8 * 8;
    const float4 v0 = *(const float4*)src;
    const float4 v1 = *(const float4*)(src + 4);
    uint32_t u[4] = {pk2(v0.x, v0.y), pk2(v0.z, v0.w),
                     pk2(v1.x, v1.y), pk2(v1.z, v1.w)};
    const int strip = i >> 4, lo = i & 15;
    const int s = c8 >> 3, kk = (c8 >> 2) & 1, hi = c8 & 3;
    *(uint4*)&Fb[(size_t)b * 262144 + (size_t)strip * 4096 + s * 1024 +
                 kk * 512 + (hi * 16 + lo) * 8] = *(uint4*)u;
  } else if (gt < 311296) {             // Wq/Wk/Wv: m(3) x c8(32) x n(512)
    const int wt = gt - 262144;
    const int m  = wt >> 14;
    const int r  = wt & 16383;
    const int n  = r & 511;             // lane-fastest -> coalesced reads
    const int c8 = r >> 9;
    const float* W = (m == 0) ? Wq : (m == 1) ? Wk : Wv;
    const float scale = (m == 0) ? QSCALE : 1.0f;
    short tmp[8];
#pragma unroll
    for (int j = 0; j < 8; ++j)
      tmp[j] = cvt1(W[(size_t)(c8 * 8 + j) * 512 + n] * scale);
    const int h = n >> 6, fm = (n >> 4) & 3, lo = n & 15;
    const int s = c8 >> 3, kk = (c8 >> 2) & 1, hi = c8 & 3;
    *(int4*)&Wtf[(size_t)(((m * 8 + h) * 4 + fm) * 4 + s) * 1024 +
                 kk * 512 + (hi * 16 + lo) * 8] = *(int4*)tmp;
  } else if (gt < 327680) {             // Wo: o(256) x k8(64)
    const int wo = gt - 311296;
    const int o  = wo >> 6;
    const int k8 = wo & 63;             // lane-fastest -> coalesced reads
    const float* src = Wo + (size_t)o * 512 + k8 * 8;
    const float4 v0 = *(const float4*)src;
    const float4 v1 = *(const float4*)(src + 4);
    uint32_t u[4] = {pk2(v0.x, v0.y), pk2(v0.z, v0.w),
                     pk2(v1.x, v1.y), pk2(v1.z, v1.w)};
    const int nt = o >> 6, fc = (o >> 4) & 3, lo = o & 15;
    const int s = k8 >> 3, kk = (k8 >> 2) & 1, hi = k8 & 3;
    *(uint4*)&Wobf[(size_t)((nt * 4 + fc) * 8 + s) * 1024 +
                   kk * 512 + (hi * 16 + lo) * 8] = *(uint4*)u;
  }
}

// ---------------------------------------------------------------------------
// K1: QKV projection, one mat per block. 1536 blocks x 256, no barriers.
// All loads fragment-ordered (coalesced).
// ---------------------------------------------------------------------------
__global__ __launch_bounds__(256, 4) void k_qkv(
    const short* __restrict__ Fb, const short* __restrict__ Wtf,
    short* __restrict__ Qf, short* __restrict__ Kf, short* __restrict__ Vf)
{
  const int hw = blockIdx.x, t = threadIdx.x;
  const int xcd  = hw & 7;
  const int slot = hw >> 3;              // 0..191
  const int mh   = slot >> 3;            // 0..23 = m*8+h
  const int g    = xcd * 8 + (slot & 7); // (b,mt), co-XCD
  const int m    = mh >> 3;
  const int h    = mh & 7;
  const int b    = g >> 3;
  const int mt   = g & 7;
  const int wv = t >> 6, l = t & 63, lo = l & 15, hi = l >> 4;

  f32x4 acc[4][2];  // [fm: d-block][fn: i-block]
#pragma unroll
  for (int i = 0; i < 4; ++i)
#pragma unroll
    for (int j = 0; j < 2; ++j) acc[i][j] = (f32x4){0.f, 0.f, 0.f, 0.f};

  const short* fbase = Fb + (size_t)b * 262144;
  const short* wbase = Wtf + (size_t)(m * 8 + h) * 16384;
  const int strip0 = mt * 8 + wv * 2;    // i-strip base for this wave

#pragma unroll
  for (int s = 0; s < 4; ++s) {
    bf16x8 bb[2][2];
#pragma unroll
    for (int fn = 0; fn < 2; ++fn)
#pragma unroll
      for (int kk = 0; kk < 2; ++kk)
        bb[fn][kk] = *(const bf16x8*)(fbase + (size_t)(strip0 + fn) * 4096 +
                                      s * 1024 + kk * 512 + l * 8);
#pragma unroll
    for (int fm = 0; fm < 4; ++fm) {
      const short* wr = wbase + (size_t)(fm * 4 + s) * 1024 + l * 8;
      bf16x8 a0 = *(const bf16x8*)(wr);
      bf16x8 a1 = *(const bf16x8*)(wr + 512);
      acc[fm][0] = MFMA(a0, bb[0][0], acc[fm][0]);
      acc[fm][1] = MFMA(a0, bb[1][0], acc[fm][1]);
      acc[fm][0] = MFMA(a1, bb[0][1], acc[fm][0]);
      acc[fm][1] = MFMA(a1, bb[1][1], acc[fm][1]);
    }
  }

  // Epilogue: lane holds (i = strip*16+lo, d = fm*16+hi*4 + 0..3).
  // Fragment-order store: kk=fm>>1, hi'=(fm&1)*2+(hi>>1), e0=(hi&1)*4.
  short* O = (m == 0) ? Qf : (m == 1) ? Kf : Vf;
  const size_t obase = (size_t)(b * 8 + h) * 65536;
#pragma unroll
  for (int fm = 0; fm < 4; ++fm)
#pragma unroll
    for (int fn = 0; fn < 2; ++fn) {
      uint32_t u[2] = {pk2(acc[fm][fn][0], acc[fm][fn][1]),
                       pk2(acc[fm][fn][2], acc[fm][fn][3])};
      const int strip = strip0 + fn;
      const int kk = fm >> 1;
      const int hip = (fm & 1) * 2 + (hi >> 1);
      const int e0 = (hi & 1) * 4;
      *(uint2*)&O[obase + (size_t)strip * 1024 + kk * 512 +
                  (hip * 16 + lo) * 8 + e0] = *(uint2*)u;
    }
}

// ---------------------------------------------------------------------------
// K2: fused colsum+rowsum with E-cache. 64*NSLICE blocks; JW=1024/NSLICE.
// Pass 1: MFMA + exp2 once; E=exp2(S') stored bf16 in LDS ([JW][1024+8
// pad] -> 2-way bank alias, free) while d_j accumulates. Pass 2: pure LDS
// reduction w_i(partial) = sum_j E[j][i]/d_j -- no MFMA/exp2/Q-stream.
// ---------------------------------------------------------------------------
template <int NSLICE>
__global__ __launch_bounds__(256, 2) void k_attw(
    const short* __restrict__ Qf, const short* __restrict__ Kf,
    float* __restrict__ Wgp)
{
  constexpr int JW = 1024 / NSLICE;   // 32
  constexpr int NS = JW / 16;         // 2
  __shared__ short E[JW][1032];       // bf16 exp2(S'), +8 short pad
  __shared__ float Red[4 * JW];
  const int hw = blockIdx.x, t = threadIdx.x;
  const int xcd  = hw & 7;
  const int slot = hw >> 3;                  // 0..8*NSLICE-1
  const int bh   = xcd * 8 + slot / NSLICE;  // same-bh blocks co-XCD
  const int jb   = slot % NSLICE;
  const size_t base = (size_t)bh * 65536;
  const int wv = t >> 6, l = t & 63, lo = l & 15, hi = l >> 4;
  const short* qb = Qf + base;
  const short* kb = Kf + base;

  bf16x8 bk[NS][2];
#pragma unroll
  for (int js = 0; js < NS; ++js) {
    const short* kr = kb + (size_t)(jb * NS + js) * 1024 + l * 8;
    bk[js][0] = *(const bf16x8*)(kr);
    bk[js][1] = *(const bf16x8*)(kr + 512);
  }

  // -------- pass 1: d_j partials + E store. Wave wv: strips wv+8k+4p.
  float cs[NS];
#pragma unroll
  for (int js = 0; js < NS; ++js) cs[js] = 0.f;

  {
    bf16x8 a0[2], a1[2];
#pragma unroll
    for (int p = 0; p < 2; ++p) {
      const short* q = qb + (size_t)(wv + 4 * p) * 1024 + l * 8;
      a0[p] = *(const bf16x8*)(q);
      a1[p] = *(const bf16x8*)(q + 512);
    }
#pragma unroll 1
    for (int k = 0; k < 8; ++k) {
      bf16x8 n0[2], n1[2];
      if (k < 7) {
#pragma unroll
        for (int p = 0; p < 2; ++p) {
          const short* q = qb + (size_t)(wv + 8 * (k + 1) + 4 * p) * 1024 + l * 8;
          n0[p] = *(const bf16x8*)(q);
          n1[p] = *(const bf16x8*)(q + 512);
        }
      }
#pragma unroll
      for (int js = 0; js < NS; ++js) {
#pragma unroll
        for (int p = 0; p < 2; ++p) {
          f32x4 acc = (f32x4){0.f, 0.f, 0.f, 0.f};
          acc = MFMA(a0[p], bk[js][0], acc);
          acc = MFMA(a1[p], bk[js][1], acc);
          // lane holds S'[i = strip*16 + hi*4 + r][j = js*16 + lo]
          float e0 = EXP2(acc[0]), e1 = EXP2(acc[1]);
          float e2 = EXP2(acc[2]), e3 = EXP2(acc[3]);
          cs[js] += (e0 + e1) + (e2 + e3);
          uint32_t u[2] = {pk2(e0, e1), pk2(e2, e3)};
          const int strip = wv + 8 * k + 4 * p;
          *(uint2*)&E[js * 16 + lo][strip * 16 + hi * 4] = *(uint2*)u;
        }
      }
      if (k < 7) {
#pragma unroll
        for (int p = 0; p < 2; ++p) { a0[p] = n0[p]; a1[p] = n1[p]; }
      }
    }
  }

#pragma unroll
  for (int js = 0; js < NS; ++js) {
    cs[js] += __shfl_xor(cs[js], 16, 64);
    cs[js] += __shfl_xor(cs[js], 32, 64);
  }
  if (hi == 0) {
#pragma unroll
    for (int js = 0; js < NS; ++js) Red[wv * JW + js * 16 + lo] = cs[js];
  }
  __syncthreads();
  if (t < JW) {
    float d = Red[t] + Red[JW + t] + Red[2 * JW + t] + Red[3 * JW + t];
    Red[t] = __builtin_amdgcn_rcpf(d);
  }
  __syncthreads();

  // -------- pass 2: pure LDS reduction. Thread t owns i = 4t..4t+3.
  {
    const int i0 = t * 4;
    float w4[4] = {0.f, 0.f, 0.f, 0.f};
#pragma unroll
    for (int j = 0; j < JW; ++j) {
      const float rjj = Red[j];                       // broadcast read
      uint2 u = *(const uint2*)&E[j][i0];
      w4[0] = fmaf(__uint_as_float(u.x << 16),          rjj, w4[0]);
      w4[1] = fmaf(__uint_as_float(u.x & 0xffff0000u),  rjj, w4[1]);
      w4[2] = fmaf(__uint_as_float(u.y << 16),          rjj, w4[2]);
      w4[3] = fmaf(__uint_as_float(u.y & 0xffff0000u),  rjj, w4[3]);
    }
    float4 o = {w4[0], w4[1], w4[2], w4[3]};
    *(float4*)&Wgp[(size_t)jb * 65536 + (size_t)bh * 1024 + i0] = o;
  }
}

// ---------------------------------------------------------------------------
// K3: out = (V .* w) @ Wob^T; w = sum of NSLICE partials (LDS prologue).
// 512 blocks x 256; all fragment loads coalesced.
// ---------------------------------------------------------------------------
template <int NSLICE>
__global__ __launch_bounds__(256, 2) void k_out(
    const short* __restrict__ Vf, const float* __restrict__ Wgp,
    const short* __restrict__ Wobf, float* __restrict__ Out)
{
  __shared__ float Wl[8][64];
  const int hw = blockIdx.x, t = threadIdx.x;
  const int slot = hw >> 3;
  const int g    = (hw & 7) * 16 + (slot >> 2);
  const int nt   = slot & 3;
  const int b    = g >> 4;
  const int mt   = g & 15;
  const int n0   = nt * 64;
  const int m0   = mt * 64;
  const int wv = t >> 6, l = t & 63, lo = l & 15, hi = l >> 4;

#pragma unroll
  for (int e = t; e < 512; e += 256) {
    int s = e >> 6, i2 = e & 63;
    float sum = 0.f;
#pragma unroll
    for (int p = 0; p < NSLICE; ++p)
      sum += Wgp[(size_t)p * 65536 + (size_t)(b * 8 + s) * 1024 + m0 + i2];
    Wl[s][i2] = sum;
  }
  __syncthreads();

  f32x4 acc[4];
#pragma unroll
  for (int j = 0; j < 4; ++j) acc[j] = (f32x4){0.f, 0.f, 0.f, 0.f};

  const int strip = mt * 4 + wv;   // i-strip (0..63)

#pragma unroll 1
  for (int s = 0; s < 8; ++s) {
    const float w = Wl[s][wv * 16 + lo];
    const short* vt = Vf + (size_t)(b * 8 + s) * 65536 + (size_t)strip * 1024;
#pragma unroll
    for (int kk = 0; kk < 2; ++kk) {
      int4 raw = *(const int4*)(vt + kk * 512 + l * 8);
      uint32_t* u = (uint32_t*)&raw;
      uint32_t o[4];
#pragma unroll
      for (int j = 0; j < 4; ++j) {
        float f0 = __uint_as_float(u[j] << 16) * w;
        float f1 = __uint_as_float(u[j] & 0xffff0000u) * w;
        o[j] = pk2(f0, f1);
      }
      bf16x8 a = *(bf16x8*)o;
#pragma unroll
      for (int fc = 0; fc < 4; ++fc) {
        bf16x8 bfr = *(const bf16x8*)(Wobf + (size_t)((nt * 4 + fc) * 8 + s) * 1024 +
                                      kk * 512 + l * 8);
        acc[fc] = MFMA(a, bfr, acc[fc]);
      }
    }
  }

#pragma unroll
  for (int fc = 0; fc < 4; ++fc)
#pragma unroll
    for (int r = 0; r < 4; ++r) {
      int i = m0 + wv * 16 + hi * 4 + r;
      int o = n0 + fc * 16 + lo;
      Out[(size_t)(b * 1024 + i) * 256 + o] = acc[fc][r];
    }
}

// ---------------------------------------------------------------------------
extern "C" void kernel_launch(void* const* d_in, const int* in_sizes, int n_in,
                              void* d_out, int out_size, void* d_ws, size_t ws_size,
                              hipStream_t stream) {
  const float* F  = (const float*)d_in[0];
  const float* Wq = (const float*)d_in[1];
  const float* Wk = (const float*)d_in[2];
  const float* Wv = (const float*)d_in[3];
  const float* Wo = (const float*)d_in[4];
  float* out = (float*)d_out;

  char* ws = (char*)d_ws;
  short* Qf   = (short*)(ws);                                      // 8 MB
  short* Kf   = (short*)(ws + (size_t)(8  << 20));                 // 8 MB
  short* Vf   = (short*)(ws + (size_t)(16 << 20));                 // 8 MB
  short* Fb   = (short*)(ws + (size_t)(24 << 20));                 // 4 MB
  float* Wgp  = (float*)(ws + (size_t)(28 << 20));                 // 8 MB (32 slices)
  short* Wtf  = (short*)(ws + (size_t)(36 << 20));                 // 768 KB
  short* Wobf = (short*)(ws + (size_t)(36 << 20) + (768 << 10));   // 256 KB

  k_prep<<<dim3(1280), 256, 0, stream>>>(F, Wq, Wk, Wv, Wo, Fb, Wtf, Wobf);
  k_qkv <<<dim3(1536), 256, 0, stream>>>(Fb, Wtf, Qf, Kf, Vf);
  k_attw<32><<<dim3(2048), 256, 0, stream>>>(Qf, Kf, Wgp);
  k_out<32> <<<dim3(512),  256, 0, stream>>>(Vf, Wgp, Wobf, out);
}